// Round 1
// baseline (431.244 us; speedup 1.0000x reference)
//
#include <hip/hip_runtime.h>

#define N_ 16384
#define D_ 256

typedef __attribute__((ext_vector_type(8))) short short8;
typedef __attribute__((ext_vector_type(4))) float floatx4;

__device__ __forceinline__ unsigned short f2bf(float x) {
  unsigned int u = __float_as_uint(x);
  u += 0x7fffu + ((u >> 16) & 1u);
  return (unsigned short)(u >> 16);
}

// ---------------- prep: fp32 -> bf16 (image pre-scaled by logit_scale*log2e) ----------------
__global__ void prep_kernel(const float* __restrict__ img, const float* __restrict__ txt,
                            const float* __restrict__ ls, short* __restrict__ Ab,
                            short* __restrict__ Bb, float* __restrict__ accv) {
  int idx = blockIdx.x * 256 + threadIdx.x;  // float4 index, N_*D_/4 total
  float s2 = ls[0] * 1.4426950408889634f;
  float4 a = ((const float4*)img)[idx];
  float4 b = ((const float4*)txt)[idx];
  short4 oa, ob;
  oa.x = (short)f2bf(a.x * s2); oa.y = (short)f2bf(a.y * s2);
  oa.z = (short)f2bf(a.z * s2); oa.w = (short)f2bf(a.w * s2);
  ob.x = (short)f2bf(b.x); ob.y = (short)f2bf(b.y);
  ob.z = (short)f2bf(b.z); ob.w = (short)f2bf(b.w);
  ((short4*)Ab)[idx] = oa;
  ((short4*)Bb)[idx] = ob;
  if (idx == 0) accv[0] = 0.0f;
}

// ---------------- diag: exact fp32 diagonal in log2 domain ----------------
__global__ void diag_kernel(const float* __restrict__ img, const float* __restrict__ txt,
                            const float* __restrict__ ls, float* __restrict__ diag2) {
  int row = blockIdx.x * 4 + (threadIdx.x >> 6);
  int lane = threadIdx.x & 63;
  float4 a = ((const float4*)(img + row * D_))[lane];
  float4 b = ((const float4*)(txt + row * D_))[lane];
  float s = a.x * b.x + a.y * b.y + a.z * b.z + a.w * b.w;
  #pragma unroll
  for (int off = 1; off < 64; off <<= 1) s += __shfl_xor(s, off);
  if (lane == 0) diag2[row] = s * ls[0] * 1.4426950408889634f;
}

// ---------------- gemm + per-tile row/col (max, sumexp2) stats ----------------
// Block tile 128x128, 8 waves (2 wave-rows x 4 wave-cols), wave tile 64x32.
// A rows pre-scaled => acc is log2-domain logits directly.
#define LDK 72  // 64 + 8 pad (2-way LDS conflict = free)

__global__ __launch_bounds__(512, 4)
void gemm_stats(const short* __restrict__ Ab, const short* __restrict__ Bb,
                float2* __restrict__ pR, float2* __restrict__ pC) {
  __shared__ short As[128][LDK];
  __shared__ short Bs[128][LDK];
  __shared__ float2 rowp[4][128];
  __shared__ float2 colp[2][128];

  const int tid = threadIdx.x;
  const int lane = tid & 63, wave = tid >> 6;
  const int q = lane >> 4, c = lane & 15;
  const int wr = wave >> 2, wc = wave & 3;
  const int ib = blockIdx.y * 128, jb = blockIdx.x * 128;

  const int srow = tid >> 3, scol = (tid & 7) * 8;
  const short* gA = Ab + (ib + srow) * D_ + scol;
  const short* gB = Bb + (jb + srow) * D_ + scol;

  floatx4 acc[4][2];
  const floatx4 fz = {0.f, 0.f, 0.f, 0.f};
  #pragma unroll
  for (int mi = 0; mi < 4; mi++)
    #pragma unroll
    for (int ni = 0; ni < 2; ni++) acc[mi][ni] = fz;

  // prologue: stage chunk 0
  short8 a0 = *(const short8*)(gA);
  short8 a1 = *(const short8*)(gA + 64 * D_);
  short8 b0 = *(const short8*)(gB);
  short8 b1 = *(const short8*)(gB + 64 * D_);
  *(short8*)&As[srow][scol] = a0;
  *(short8*)&As[srow + 64][scol] = a1;
  *(short8*)&Bs[srow][scol] = b0;
  *(short8*)&Bs[srow + 64][scol] = b1;
  __syncthreads();

  #pragma unroll
  for (int kc = 0; kc < 4; ++kc) {
    if (kc < 3) {  // register prefetch of next K-chunk overlaps compute
      const short* pAn = gA + (kc + 1) * 64;
      const short* pBn = gB + (kc + 1) * 64;
      a0 = *(const short8*)(pAn);
      a1 = *(const short8*)(pAn + 64 * D_);
      b0 = *(const short8*)(pBn);
      b1 = *(const short8*)(pBn + 64 * D_);
    }
    #pragma unroll
    for (int ks = 0; ks < 2; ++ks) {
      short8 af[4], bf[2];
      int ko = ks * 32 + q * 8;
      #pragma unroll
      for (int mi = 0; mi < 4; mi++)
        af[mi] = *(const short8*)&As[wr * 64 + mi * 16 + c][ko];
      #pragma unroll
      for (int ni = 0; ni < 2; ni++)
        bf[ni] = *(const short8*)&Bs[wc * 32 + ni * 16 + c][ko];
      #pragma unroll
      for (int mi = 0; mi < 4; mi++)
        #pragma unroll
        for (int ni = 0; ni < 2; ni++)
          acc[mi][ni] = __builtin_amdgcn_mfma_f32_16x16x32_bf16(af[mi], bf[ni], acc[mi][ni], 0, 0, 0);
    }
    if (kc < 3) {
      __syncthreads();
      *(short8*)&As[srow][scol] = a0;
      *(short8*)&As[srow + 64][scol] = a1;
      *(short8*)&Bs[srow][scol] = b0;
      *(short8*)&Bs[srow + 64][scol] = b1;
      __syncthreads();
    }
  }

  // ---- in-register stats. acc[mi][ni][r] = logit2 at row wr*64+mi*16+q*4+r, col wc*32+ni*16+c
  // Row stats: reduce over ni and the 16-lane c group (xor 1/2/4/8)
  #pragma unroll
  for (int mi = 0; mi < 4; mi++) {
    #pragma unroll
    for (int r = 0; r < 4; r++) {
      float m = fmaxf(acc[mi][0][r], acc[mi][1][r]);
      #pragma unroll
      for (int off = 1; off < 16; off <<= 1) m = fmaxf(m, __shfl_xor(m, off));
      float s = exp2f(acc[mi][0][r] - m) + exp2f(acc[mi][1][r] - m);
      #pragma unroll
      for (int off = 1; off < 16; off <<= 1) s += __shfl_xor(s, off);
      if (c == 0) rowp[wc][wr * 64 + mi * 16 + q * 4 + r] = make_float2(m, s);
    }
  }
  // Col stats: reduce over mi,r and the q groups (xor 16/32)
  #pragma unroll
  for (int ni = 0; ni < 2; ni++) {
    float m = acc[0][ni][0];
    #pragma unroll
    for (int mi = 0; mi < 4; mi++)
      #pragma unroll
      for (int r = 0; r < 4; r++) m = fmaxf(m, acc[mi][ni][r]);
    m = fmaxf(m, __shfl_xor(m, 16));
    m = fmaxf(m, __shfl_xor(m, 32));
    float s = 0.f;
    #pragma unroll
    for (int mi = 0; mi < 4; mi++)
      #pragma unroll
      for (int r = 0; r < 4; r++) s += exp2f(acc[mi][ni][r] - m);
    s += __shfl_xor(s, 16);
    s += __shfl_xor(s, 32);
    if (q == 0) colp[wr][wc * 32 + ni * 16 + c] = make_float2(m, s);
  }
  __syncthreads();

  // ---- cross-wave merge + write partials
  if (tid < 128) {
    int i = tid;
    float2 p0 = rowp[0][i], p1 = rowp[1][i], p2 = rowp[2][i], p3 = rowp[3][i];
    float m = fmaxf(fmaxf(p0.x, p1.x), fmaxf(p2.x, p3.x));
    float l = p0.y * exp2f(p0.x - m) + p1.y * exp2f(p1.x - m) +
              p2.y * exp2f(p2.x - m) + p3.y * exp2f(p3.x - m);
    pR[blockIdx.x * N_ + ib + i] = make_float2(m, l);
  } else if (tid < 256) {
    int j = tid - 128;
    float2 p0 = colp[0][j], p1 = colp[1][j];
    float m = fmaxf(p0.x, p1.x);
    float l = p0.y * exp2f(p0.x - m) + p1.y * exp2f(p1.x - m);
    pC[blockIdx.y * N_ + jb + j] = make_float2(m, l);
  }
}

// ---------------- merge 128 tile-partials per row/col -> LSE -> loss sum ----------------
__global__ void merge_kernel(const float2* __restrict__ pR, const float2* __restrict__ pC,
                             const float* __restrict__ diag2, float* __restrict__ accv) {
  int idx = blockIdx.x * 256 + threadIdx.x;  // 0..2N-1
  const float2* src;
  int i;
  if (idx < N_) { src = pR; i = idx; }
  else          { src = pC; i = idx - N_; }
  float2 v = src[i];
  float M = v.x, L = v.y;
  for (int j = 1; j < 128; ++j) {
    float2 w = src[j * N_ + i];
    float nm = fmaxf(M, w.x);
    L = L * exp2f(M - nm) + w.y * exp2f(w.x - nm);
    M = nm;
  }
  float val = (M + log2f(L)) - diag2[i];

  __shared__ float red[256];
  red[threadIdx.x] = val;
  __syncthreads();
  #pragma unroll
  for (int s = 128; s > 0; s >>= 1) {
    if (threadIdx.x < s) red[threadIdx.x] += red[threadIdx.x + s];
    __syncthreads();
  }
  if (threadIdx.x == 0) atomicAdd(accv, red[0]);
}

__global__ void finalize_kernel(const float* __restrict__ accv, float* __restrict__ out) {
  // loss = ln2 * acc / (2N)
  out[0] = accv[0] * (0.69314718055994531f / 32768.0f);
}

// ---------------- launch ----------------
extern "C" void kernel_launch(void* const* d_in, const int* in_sizes, int n_in,
                              void* d_out, int out_size, void* d_ws, size_t ws_size,
                              hipStream_t stream) {
  const float* img = (const float*)d_in[0];
  const float* txt = (const float*)d_in[1];
  const float* ls  = (const float*)d_in[2];
  float* out = (float*)d_out;

  char* ws = (char*)d_ws;
  short* Ab    = (short*)(ws);                       //  8388608 B
  short* Bb    = (short*)(ws + 8388608);             //  8388608 B
  float* diag2 = (float*)(ws + 16777216);            //    65536 B
  float* accv  = (float*)(ws + 16842752);            //      256 B
  float2* pR   = (float2*)(ws + 16843008);           // 16777216 B
  float2* pC   = (float2*)(ws + 33620224);           // 16777216 B  (end ~48.1 MB)

  hipLaunchKernelGGL(prep_kernel, dim3((N_ * D_ / 4) / 256), dim3(256), 0, stream,
                     img, txt, ls, Ab, Bb, accv);
  hipLaunchKernelGGL(diag_kernel, dim3(N_ / 4), dim3(256), 0, stream, img, txt, ls, diag2);
  hipLaunchKernelGGL(gemm_stats, dim3(N_ / 128, N_ / 128), dim3(512), 0, stream, Ab, Bb, pR, pC);
  hipLaunchKernelGGL(merge_kernel, dim3(2 * N_ / 256), dim3(256), 0, stream, pR, pC, diag2, accv);
  hipLaunchKernelGGL(finalize_kernel, dim3(1), dim3(1), 0, stream, accv, out);
}

// Round 3
// 316.715 us; speedup vs baseline: 1.3616x; 1.3616x over previous
//
#include <hip/hip_runtime.h>

#define N_ 16384
#define D_ 256

typedef __attribute__((ext_vector_type(8))) short short8;
typedef __attribute__((ext_vector_type(16))) float floatx16;

typedef __attribute__((address_space(1))) const unsigned int gu32_t;
typedef __attribute__((address_space(3))) unsigned int lu32_t;

__device__ __forceinline__ void async16(const void* g, void* l) {
  __builtin_amdgcn_global_load_lds((gu32_t*)g, (lu32_t*)l, 16, 0, 0);
}

__device__ __forceinline__ unsigned short f2bf(float x) {
  unsigned int u = __float_as_uint(x);
  u += 0x7fffu + ((u >> 16) & 1u);
  return (unsigned short)(u >> 16);
}

// ---------------- prep: fp32 -> bf16 (image pre-scaled by logit_scale*log2e) ----------------
__global__ void prep_kernel(const float* __restrict__ img, const float* __restrict__ txt,
                            const float* __restrict__ ls, short* __restrict__ Ab,
                            short* __restrict__ Bb, float* __restrict__ accv) {
  int idx = blockIdx.x * 256 + threadIdx.x;
  float s2 = ls[0] * 1.4426950408889634f;
  float4 a = ((const float4*)img)[idx];
  float4 b = ((const float4*)txt)[idx];
  short4 oa, ob;
  oa.x = (short)f2bf(a.x * s2); oa.y = (short)f2bf(a.y * s2);
  oa.z = (short)f2bf(a.z * s2); oa.w = (short)f2bf(a.w * s2);
  ob.x = (short)f2bf(b.x); ob.y = (short)f2bf(b.y);
  ob.z = (short)f2bf(b.z); ob.w = (short)f2bf(b.w);
  ((short4*)Ab)[idx] = oa;
  ((short4*)Bb)[idx] = ob;
  if (idx == 0) accv[0] = 0.0f;
}

// ---------------- diag: exact fp32 diagonal in log2 domain ----------------
__global__ void diag_kernel(const float* __restrict__ img, const float* __restrict__ txt,
                            const float* __restrict__ ls, float* __restrict__ diag2) {
  int row = blockIdx.x * 4 + (threadIdx.x >> 6);
  int lane = threadIdx.x & 63;
  float4 a = ((const float4*)(img + row * D_))[lane];
  float4 b = ((const float4*)(txt + row * D_))[lane];
  float s = a.x * b.x + a.y * b.y + a.z * b.z + a.w * b.w;
  #pragma unroll
  for (int off = 1; off < 64; off <<= 1) s += __shfl_xor(s, off);
  if (lane == 0) diag2[row] = s * ls[0] * 1.4426950408889634f;
}

// ---------------- gemm + per-slab-max row/col sumexp2 partials ----------------
// Block 128x128, 256 threads = 4 waves in 2x2, wave tile 64x64 = 2x2 of mfma 32x32x16.
// Staging via global_load_lds(16B) into unpadded [row][64] LDS with XOR k-chunk swizzle.
// Shared max per slab (32 rows x 128 cols) with -90 offset; zero-skip merges make this safe.
__global__ __launch_bounds__(256, 4)
void gemm_stats(const short* __restrict__ Ab, const short* __restrict__ Bb,
                float2* __restrict__ pR, float2* __restrict__ pC) {
  __shared__ char smem[35872];
  // staging phase: As = smem[0..16383], Bs = smem[16384..32767]
  // epilogue phase (overlaps staging): rowbuf f32[64][132] @0 (33792 B)
  // colbuf f32[4][128] @33792, wmaxb f32[4][2] @35840
  short* As = (short*)smem;
  short* Bs = (short*)(smem + 16384);
  float* rowbuf = (float*)smem;
  float* colbuf = (float*)(smem + 33792);
  float* wmaxb  = (float*)(smem + 35840);

  const int tid = threadIdx.x;
  const int wv = tid >> 6, lane = tid & 63;
  const int wr = wv >> 1, wc = wv & 1;
  const int m = lane & 31, h = lane >> 5, x = m & 7;
  const int ib = blockIdx.y * 128, jb = blockIdx.x * 128;

  // ---- staging setup: thread loads 16B: row = (tid>>3)+32*rd, phys chunk = tid&7,
  // global k-chunk = (tid&7) ^ (row&7)  (row&7 invariant across rd)
  const int srow = tid >> 3;
  const int gcol = ((tid & 7) ^ (srow & 7)) * 8;
  const short* gA = Ab + (size_t)(ib + srow) * D_ + gcol;
  const short* gB = Bb + (size_t)(jb + srow) * D_ + gcol;

  // ---- fragment LDS byte offsets (constant across kc): A row = wr*64+ti*32+m,
  // phys chunk p = (ks*2+h) ^ (row&7); same form for B with wc/ni.
  int aoff[2][4], boff[2][4];
  #pragma unroll
  for (int ti = 0; ti < 2; ++ti)
    #pragma unroll
    for (int ks = 0; ks < 4; ++ks)
      aoff[ti][ks] = (wr * 64 + ti * 32 + m) * 128 + (((ks * 2 + h) ^ x) * 16);
  #pragma unroll
  for (int ni = 0; ni < 2; ++ni)
    #pragma unroll
    for (int ks = 0; ks < 4; ++ks)
      boff[ni][ks] = (wc * 64 + ni * 32 + m) * 128 + (((ks * 2 + h) ^ x) * 16);

  floatx16 acc[2][2];
  #pragma unroll
  for (int ti = 0; ti < 2; ++ti)
    #pragma unroll
    for (int ni = 0; ni < 2; ++ni)
      #pragma unroll
      for (int r = 0; r < 16; ++r) acc[ti][ni][r] = 0.f;

  for (int kc = 0; kc < 4; ++kc) {
    #pragma unroll
    for (int rd = 0; rd < 4; ++rd) {
      async16(gA + rd * 32 * D_ + kc * 64, smem + wv * 1024 + rd * 4096);
      async16(gB + rd * 32 * D_ + kc * 64, smem + 16384 + wv * 1024 + rd * 4096);
    }
    asm volatile("s_waitcnt vmcnt(0)" ::: "memory");
    __syncthreads();
    #pragma unroll
    for (int ks = 0; ks < 4; ++ks) {
      short8 a0 = *(const short8*)((char*)As + aoff[0][ks]);
      short8 a1 = *(const short8*)((char*)As + aoff[1][ks]);
      short8 b0 = *(const short8*)((char*)Bs + boff[0][ks]);
      short8 b1 = *(const short8*)((char*)Bs + boff[1][ks]);
      acc[0][0] = __builtin_amdgcn_mfma_f32_32x32x16_bf16(a0, b0, acc[0][0], 0, 0, 0);
      acc[0][1] = __builtin_amdgcn_mfma_f32_32x32x16_bf16(a0, b1, acc[0][1], 0, 0, 0);
      acc[1][0] = __builtin_amdgcn_mfma_f32_32x32x16_bf16(a1, b0, acc[1][0], 0, 0, 0);
      acc[1][1] = __builtin_amdgcn_mfma_f32_32x32x16_bf16(a1, b1, acc[1][1], 0, 0, 0);
    }
    __syncthreads();
  }

  // ---- epilogue. Element (ti,ni,reg): row R = wr*64+ti*32+(reg&3)+8*(reg>>2)+4*h,
  //                                     col J = wc*64+ni*32+m
  // slab = wr*2+ti (32 rows x full 128 cols)
  // 1) per-slab max (wave butterfly + cross-wcol via LDS)
  #pragma unroll
  for (int ti = 0; ti < 2; ++ti) {
    float v = acc[ti][0][0];
    #pragma unroll
    for (int ni = 0; ni < 2; ++ni)
      #pragma unroll
      for (int r = 0; r < 16; ++r) v = fmaxf(v, acc[ti][ni][r]);
    #pragma unroll
    for (int off = 1; off < 64; off <<= 1) v = fmaxf(v, __shfl_xor(v, off));
    if (lane == 0) wmaxb[(wr * 2 + ti) * 2 + wc] = v;
  }
  __syncthreads();
  float meff[2];
  #pragma unroll
  for (int ti = 0; ti < 2; ++ti)
    meff[ti] = fmaxf(wmaxb[(wr * 2 + ti) * 2 + 0], wmaxb[(wr * 2 + ti) * 2 + 1]) - 90.f;

  // 2) exp2 in place (one per logit)
  #pragma unroll
  for (int ti = 0; ti < 2; ++ti)
    #pragma unroll
    for (int ni = 0; ni < 2; ++ni)
      #pragma unroll
      for (int r = 0; r < 16; ++r)
        acc[ti][ni][r] = exp2f(acc[ti][ni][r] - meff[ti]);

  // 3) col partials: register-local sum over 16 regs, + cross-h shuffle
  #pragma unroll
  for (int ti = 0; ti < 2; ++ti)
    #pragma unroll
    for (int ni = 0; ni < 2; ++ni) {
      float cp = 0.f;
      #pragma unroll
      for (int r = 0; r < 16; ++r) cp += acc[ti][ni][r];
      cp += __shfl_xor(cp, 32);
      if (h == 0) colbuf[(wr * 2 + ti) * 128 + wc * 64 + ni * 32 + m] = cp;
    }

  // 4) row partials: pack 4 consecutive rows -> b128 into rowbuf[cslot][R]
  #pragma unroll
  for (int ti = 0; ti < 2; ++ti)
    #pragma unroll
    for (int a = 0; a < 4; ++a) {
      float4 rp;
      rp.x = acc[ti][0][a * 4 + 0] + acc[ti][1][a * 4 + 0];
      rp.y = acc[ti][0][a * 4 + 1] + acc[ti][1][a * 4 + 1];
      rp.z = acc[ti][0][a * 4 + 2] + acc[ti][1][a * 4 + 2];
      rp.w = acc[ti][0][a * 4 + 3] + acc[ti][1][a * 4 + 3];
      int cslot = wc * 32 + m;
      int R0 = wr * 64 + ti * 32 + a * 8 + h * 4;
      *(float4*)&rowbuf[cslot * 132 + R0] = rp;
    }
  __syncthreads();

  // 5) phase2 rows: 2 threads per row sum 64 cslots (same slab max -> plain sum)
  {
    int R = tid >> 1, half = tid & 1;
    float s = 0.f;
    #pragma unroll
    for (int k2 = 0; k2 < 32; ++k2) s += rowbuf[(half * 32 + k2) * 132 + R];
    s += __shfl_xor(s, 1);
    if (half == 0) {
      int slab = R >> 5;
      float M = fmaxf(wmaxb[slab * 2 + 0], wmaxb[slab * 2 + 1]) - 90.f;
      pR[(size_t)blockIdx.x * N_ + ib + R] = make_float2(M, s);
    }
  }
  // 6) phase2 cols: zero-skip online merge of the 4 slab partials
  if (tid < 128) {
    int j = tid;
    float M = -3.0e38f, L = 0.f;
    #pragma unroll
    for (int s4 = 0; s4 < 4; ++s4) {
      float m2 = fmaxf(wmaxb[s4 * 2 + 0], wmaxb[s4 * 2 + 1]) - 90.f;
      float l2 = colbuf[s4 * 128 + j];
      if (l2 > 0.f) {
        if (m2 > M) { L = L * exp2f(M - m2) + l2; M = m2; }
        else        { L += l2 * exp2f(m2 - M); }
      }
    }
    pC[(size_t)blockIdx.y * N_ + jb + j] = make_float2(M, L);
  }
}

// ---------------- merge 128 tile-partials per row/col (zero-skip) -> LSE -> loss sum ----------------
__global__ void merge_kernel(const float2* __restrict__ pR, const float2* __restrict__ pC,
                             const float* __restrict__ diag2, float* __restrict__ accv) {
  int idx = blockIdx.x * 256 + threadIdx.x;  // 0..2N-1
  const float2* src;
  int i;
  if (idx < N_) { src = pR; i = idx; }
  else          { src = pC; i = idx - N_; }
  float M = -3.0e38f, L = 0.f;
  for (int j = 0; j < 128; ++j) {
    float2 w = src[(size_t)j * N_ + i];
    if (w.y > 0.f) {
      if (w.x > M) { L = L * exp2f(M - w.x) + w.y; M = w.x; }
      else         { L += w.y * exp2f(w.x - M); }
    }
  }
  float val = (M + log2f(fmaxf(L, 1e-45f))) - diag2[i];

  __shared__ float red[256];
  red[threadIdx.x] = val;
  __syncthreads();
  #pragma unroll
  for (int s = 128; s > 0; s >>= 1) {
    if (threadIdx.x < s) red[threadIdx.x] += red[threadIdx.x + s];
    __syncthreads();
  }
  if (threadIdx.x == 0) atomicAdd(accv, red[0]);
}

__global__ void finalize_kernel(const float* __restrict__ accv, float* __restrict__ out) {
  out[0] = accv[0] * (0.69314718055994531f / 32768.0f);  // ln2 / (2N)
}

// ---------------- launch ----------------
extern "C" void kernel_launch(void* const* d_in, const int* in_sizes, int n_in,
                              void* d_out, int out_size, void* d_ws, size_t ws_size,
                              hipStream_t stream) {
  const float* img = (const float*)d_in[0];
  const float* txt = (const float*)d_in[1];
  const float* ls  = (const float*)d_in[2];
  float* out = (float*)d_out;

  char* ws = (char*)d_ws;
  short* Ab    = (short*)(ws);
  short* Bb    = (short*)(ws + 8388608);
  float* diag2 = (float*)(ws + 16777216);
  float* accv  = (float*)(ws + 16842752);
  float2* pR   = (float2*)(ws + 16843008);
  float2* pC   = (float2*)(ws + 33620224);

  hipLaunchKernelGGL(prep_kernel, dim3((N_ * D_ / 4) / 256), dim3(256), 0, stream,
                     img, txt, ls, Ab, Bb, accv);
  hipLaunchKernelGGL(diag_kernel, dim3(N_ / 4), dim3(256), 0, stream, img, txt, ls, diag2);
  hipLaunchKernelGGL(gemm_stats, dim3(N_ / 128, N_ / 128), dim3(256), 0, stream, Ab, Bb, pR, pC);
  hipLaunchKernelGGL(merge_kernel, dim3(2 * N_ / 256), dim3(256), 0, stream, pR, pC, diag2, accv);
  hipLaunchKernelGGL(finalize_kernel, dim3(1), dim3(1), 0, stream, accv, out);
}